// Round 1
// baseline (689.094 us; speedup 1.0000x reference)
//
#include <hip/hip_runtime.h>

typedef unsigned short ushort_t;
typedef __attribute__((ext_vector_type(8))) short bf16x8;
typedef __attribute__((ext_vector_type(4))) float f32x4;

__device__ __forceinline__ ushort_t f2bf(float f) {
    union { float f; unsigned u; } v; v.f = f;
    unsigned r = v.u + 0x7FFFu + ((v.u >> 16) & 1u);
    return (ushort_t)(r >> 16);
}
__device__ __forceinline__ float siluf(float x) { return x / (1.f + __expf(-x)); }
__device__ __forceinline__ float sigm(float x)  { return 1.f / (1.f + __expf(-x)); }

__device__ __forceinline__ void gl2lds16(const void* g, void* l) {
    __builtin_amdgcn_global_load_lds(
        (__attribute__((address_space(1))) void*)(const_cast<void*>(g)),
        (__attribute__((address_space(3))) void*)(l), 16, 0, 0);
}

// ---------------- tiny precompute kernels ----------------

// c_e[b][n] = b_epe[n] + sum_t t_pe[b][t]*W_epe[(512+t)*512+n]
// c_v[b][n] = b_vpe[n] + sum_t t_pe[b][t]*W_vpe[(456+t)*256+n]
__global__ void k_prep(const float* t_pe, const float* W_vpe, const float* b_vpe,
                       const float* W_epe, const float* b_epe,
                       float* c_v, float* c_e) {
    int b = blockIdx.x, t = threadIdx.x;  // 512 threads
    {
        float acc = b_epe[t];
        for (int u = 0; u < 100; ++u) acc += t_pe[b*100+u] * W_epe[(512+u)*512 + t];
        c_e[b*512 + t] = acc;
    }
    if (t < 256) {
        float acc = b_vpe[t];
        for (int u = 0; u < 100; ++u) acc += t_pe[b*100+u] * W_vpe[(456+u)*256 + t];
        c_v[b*256 + t] = acc;
    }
}

// transpose+bf16 weights: WT[n*512+k] = bf16(W[k*512+n]) for 3 matrices
__global__ void k_transpose(const float* W_epe, const float* W_ev1, const float* W_ev2,
                            ushort_t* WT_epe, ushort_t* WT_c, ushort_t* WT_ev2) {
    int n = blockIdx.x;
    int mat = blockIdx.y;
    const float* src; ushort_t* dst;
    if (mat == 0)      { src = W_epe;            dst = WT_epe; }
    else if (mat == 1) { src = W_ev1 + 512*512;  dst = WT_c;   }
    else               { src = W_ev2;            dst = WT_ev2; }
    for (int k = threadIdx.x; k < 512; k += 256)
        dst[n*512 + k] = f2bf(src[k*512 + n]);
}

// v = silu(v_f@W_vpe[0:256] + p_pe@W_vpe[256:456] + c_v[b]) ; 4 rows/block, 256 thr
__global__ void k_node_v(const float* v_f, const float* p_pe, const float* W_vpe,
                         const float* c_v, float* v) {
    __shared__ float rv[4][256];
    __shared__ float rp[4][200];
    int r0 = blockIdx.x * 4, t = threadIdx.x;
    for (int rr = 0; rr < 4; ++rr) {
        rv[rr][t] = v_f[(r0+rr)*256 + t];
        if (t < 200) rp[rr][t] = p_pe[(r0+rr)*200 + t];
    }
    __syncthreads();
    int b = r0 >> 7;
    float acc[4];
    float cv = c_v[b*256 + t];
    for (int rr = 0; rr < 4; ++rr) acc[rr] = cv;
    for (int k = 0; k < 256; ++k) {
        float w = W_vpe[k*256 + t];
        #pragma unroll
        for (int rr = 0; rr < 4; ++rr) acc[rr] += rv[rr][k] * w;
    }
    for (int k = 0; k < 200; ++k) {
        float w = W_vpe[(256+k)*256 + t];
        #pragma unroll
        for (int rr = 0; rr < 4; ++rr) acc[rr] += rp[rr][k] * w;
    }
    for (int rr = 0; rr < 4; ++rr) v[(r0+rr)*256 + t] = siluf(acc[rr]);
}

// 5 projections of v (256 -> 512): q, k, vs(silu), P(+b_ev1), Q ; 4 rows/block
__global__ void k_node_proj(const float* v,
                            const float* W_q, const float* b_q,
                            const float* W_k, const float* b_k,
                            const float* W_self, const float* b_self,
                            const float* W_ev1, const float* b_ev1,
                            float* q, float* kk, float* vs, float* P, float* Q) {
    __shared__ float rv[4][256];
    int r0 = blockIdx.x * 4, which = blockIdx.y, t = threadIdx.x;
    for (int rr = 0; rr < 4; ++rr) rv[rr][t] = v[(r0+rr)*256 + t];
    __syncthreads();
    const float* W; const float* bias = nullptr; float* out; bool do_silu = false;
    if (which == 0)      { W = W_q;    bias = b_q;    out = q;  }
    else if (which == 1) { W = W_k;    bias = b_k;    out = kk; }
    else if (which == 2) { W = W_self; bias = b_self; out = vs; do_silu = true; }
    else if (which == 3) { W = W_ev1;  bias = b_ev1;  out = P;  }
    else                 { W = W_ev1 + 256*512;       out = Q;  }
    float acc[4][2] = {};
    for (int k = 0; k < 256; ++k) {
        float w0 = W[k*512 + t];
        float w1 = W[k*512 + t + 256];
        #pragma unroll
        for (int rr = 0; rr < 4; ++rr) {
            acc[rr][0] += rv[rr][k] * w0;
            acc[rr][1] += rv[rr][k] * w1;
        }
    }
    float bb0 = bias ? bias[t] : 0.f;
    float bb1 = bias ? bias[t + 256] : 0.f;
    for (int rr = 0; rr < 4; ++rr) {
        float x0 = acc[rr][0] + bb0;
        float x1 = acc[rr][1] + bb1;
        if (do_silu) { x0 = siluf(x0); x1 = siluf(x1); }
        out[(r0+rr)*512 + t]       = x0;
        out[(r0+rr)*512 + t + 256] = x1;
    }
}

// ---------------- big MFMA GEMMs (M=65536, K=512, N=512) ----------------
// 128x128 tile, 4 waves (2x2 of 64x64), mfma_f32_16x16x32_bf16, BK=32.

// G1: A = e_f fp32 (inline convert), B = WT_epe ; out = bf16 silu(x + c_e[b][n])
__global__ __launch_bounds__(256) void k_gemm1(const float* Ef, const ushort_t* BT,
                                               const float* c_e, ushort_t* Eout) {
    __shared__ __align__(16) ushort_t As[128*40];  // padded stride 40 (80B, conflict-light)
    __shared__ __align__(16) ushort_t Bs[128*32];
    int m0 = blockIdx.x * 128, n0 = blockIdx.y * 128;
    int t = threadIdx.x;
    int wv = t >> 6, lane = t & 63;
    int wm = (wv >> 1) * 64, wn = (wv & 1) * 64;
    int ml = lane & 15, quad = lane >> 4;
    f32x4 acc[4][4] = {};

    int arow = t >> 1, acol = (t & 1) * 16;
    const float* gA = Ef + (size_t)(m0 + arow) * 512 + acol;
    int brow = t >> 2, bseg = t & 3;
    const ushort_t* gB0 = BT + (size_t)(n0 + brow) * 512 + bseg * 8;
    const ushort_t* gB1 = BT + (size_t)(n0 + 64 + brow) * 512 + bseg * 8;
    ushort_t* lB0 = Bs + wv * 512;
    ushort_t* lB1 = Bs + 2048 + wv * 512;

    for (int kk = 0; kk < 512; kk += 32) {
        gl2lds16(gB0 + kk, lB0);
        gl2lds16(gB1 + kk, lB1);
        const float* ga = gA + kk;
        float4 f0 = *(const float4*)(ga);
        float4 f1 = *(const float4*)(ga + 4);
        float4 f2 = *(const float4*)(ga + 8);
        float4 f3 = *(const float4*)(ga + 12);
        ushort_t* d = As + arow * 40 + acol;
        ((ushort4*)d)[0] = make_ushort4(f2bf(f0.x), f2bf(f0.y), f2bf(f0.z), f2bf(f0.w));
        ((ushort4*)d)[1] = make_ushort4(f2bf(f1.x), f2bf(f1.y), f2bf(f1.z), f2bf(f1.w));
        ((ushort4*)d)[2] = make_ushort4(f2bf(f2.x), f2bf(f2.y), f2bf(f2.z), f2bf(f2.w));
        ((ushort4*)d)[3] = make_ushort4(f2bf(f3.x), f2bf(f3.y), f2bf(f3.z), f2bf(f3.w));
        __syncthreads();
        bf16x8 a[4], b[4];
        #pragma unroll
        for (int tm = 0; tm < 4; ++tm)
            a[tm] = *(const bf16x8*)(As + (wm + tm*16 + ml) * 40 + quad * 8);
        #pragma unroll
        for (int tn = 0; tn < 4; ++tn)
            b[tn] = *(const bf16x8*)(Bs + (wn + tn*16 + ml) * 32 + quad * 8);
        #pragma unroll
        for (int tm = 0; tm < 4; ++tm)
            #pragma unroll
            for (int tn = 0; tn < 4; ++tn)
                acc[tm][tn] = __builtin_amdgcn_mfma_f32_16x16x32_bf16(a[tm], b[tn], acc[tm][tn], 0, 0, 0);
        __syncthreads();
    }
    #pragma unroll
    for (int tm = 0; tm < 4; ++tm)
        #pragma unroll
        for (int tn = 0; tn < 4; ++tn)
            #pragma unroll
            for (int r = 0; r < 4; ++r) {
                int gm = m0 + wm + tm*16 + quad*4 + r;
                int gn = n0 + wn + tn*16 + ml;
                float x = acc[tm][tn][r] + c_e[(gm >> 14)*512 + gn];
                Eout[(size_t)gm*512 + gn] = f2bf(siluf(x));
            }
}

// G2 (MODE 0): A=e16, B=WT_c, epi silu(x + P[b,i] + Q[b,j]) -> bf16 h16
// G3 (MODE 1): A=h16, B=WT_ev2, epi x + b_ev2 -> fp32 e_value
template <int MODE>
__global__ __launch_bounds__(256) void k_gemm_b(const ushort_t* A, const ushort_t* BT,
                                                const float* x0, const float* x1,
                                                ushort_t* out16, float* out32) {
    __shared__ __align__(16) ushort_t As[128*32];
    __shared__ __align__(16) ushort_t Bs[128*32];
    int m0 = blockIdx.x * 128, n0 = blockIdx.y * 128;
    int t = threadIdx.x;
    int wv = t >> 6, lane = t & 63;
    int wm = (wv >> 1) * 64, wn = (wv & 1) * 64;
    int ml = lane & 15, quad = lane >> 4;
    f32x4 acc[4][4] = {};

    int srow = t >> 2, sseg = t & 3;
    const ushort_t* gA0 = A + (size_t)(m0 + srow) * 512 + sseg * 8;
    const ushort_t* gA1 = A + (size_t)(m0 + 64 + srow) * 512 + sseg * 8;
    const ushort_t* gB0 = BT + (size_t)(n0 + srow) * 512 + sseg * 8;
    const ushort_t* gB1 = BT + (size_t)(n0 + 64 + srow) * 512 + sseg * 8;
    ushort_t* lA0 = As + wv * 512;
    ushort_t* lA1 = As + 2048 + wv * 512;
    ushort_t* lB0 = Bs + wv * 512;
    ushort_t* lB1 = Bs + 2048 + wv * 512;

    for (int kk = 0; kk < 512; kk += 32) {
        gl2lds16(gA0 + kk, lA0);
        gl2lds16(gA1 + kk, lA1);
        gl2lds16(gB0 + kk, lB0);
        gl2lds16(gB1 + kk, lB1);
        __syncthreads();
        bf16x8 a[4], b[4];
        #pragma unroll
        for (int tm = 0; tm < 4; ++tm)
            a[tm] = *(const bf16x8*)(As + (wm + tm*16 + ml) * 32 + quad * 8);
        #pragma unroll
        for (int tn = 0; tn < 4; ++tn)
            b[tn] = *(const bf16x8*)(Bs + (wn + tn*16 + ml) * 32 + quad * 8);
        #pragma unroll
        for (int tm = 0; tm < 4; ++tm)
            #pragma unroll
            for (int tn = 0; tn < 4; ++tn)
                acc[tm][tn] = __builtin_amdgcn_mfma_f32_16x16x32_bf16(a[tm], b[tn], acc[tm][tn], 0, 0, 0);
        __syncthreads();
    }
    #pragma unroll
    for (int tm = 0; tm < 4; ++tm)
        #pragma unroll
        for (int tn = 0; tn < 4; ++tn)
            #pragma unroll
            for (int r = 0; r < 4; ++r) {
                int gm = m0 + wm + tm*16 + quad*4 + r;
                int gn = n0 + wn + tn*16 + ml;
                float x = acc[tm][tn][r];
                if (MODE == 0) {
                    int b_ = gm >> 14, ij = gm & 16383, i = ij >> 7, j = ij & 127;
                    x += x0[(size_t)((b_ << 7) + i) * 512 + gn] + x1[(size_t)((b_ << 7) + j) * 512 + gn];
                    out16[(size_t)gm*512 + gn] = f2bf(siluf(x));
                } else {
                    x += x0[gn];
                    out32[(size_t)gm*512 + gn] = x;
                }
            }
}

// ---------------- attention aggregation ----------------
// per (b,i): s[j][g] = sigmoid(dot16(q,k)/sqrt(48))*mask ; normalize over j ;
// agg_v[d] = sum_j a[j][d>>4]*e_value[b,i,j,d] ; v2 = agg_v + vs
__global__ __launch_bounds__(256) void k_attn(const float* q, const float* kmat,
                                              const float* emask, const float* evalue,
                                              const float* vs, float* v2) {
    int bi = blockIdx.x; int b = bi >> 7, i = bi & 127;
    int t = threadIdx.x;
    __shared__ __align__(16) float qrow[512];
    __shared__ float s[128][33];
    __shared__ float invd[32];
    qrow[t]       = q[(size_t)bi*512 + t];
    qrow[t + 256] = q[(size_t)bi*512 + t + 256];
    __syncthreads();
    {
        int j = t >> 1, g0 = (t & 1) * 16;
        const float* kr = kmat + ((size_t)b*128 + j) * 512;
        float msk = emask[(size_t)b*16384 + i*128 + j];
        for (int gg = 0; gg < 16; ++gg) {
            int g = g0 + gg;
            const float4* k4 = (const float4*)(kr + g*16);
            const float4* q4 = (const float4*)(qrow + g*16);
            float acc = 0.f;
            #pragma unroll
            for (int c = 0; c < 4; ++c) {
                float4 kv = k4[c], qv = q4[c];
                acc += kv.x*qv.x + kv.y*qv.y + kv.z*qv.z + kv.w*qv.w;
            }
            s[j][g] = sigm(acc * 0.14433756729740645f) * msk;
        }
    }
    __syncthreads();
    if (t < 32) {
        float d = 1e-6f;
        for (int j = 0; j < 128; ++j) d += s[j][t];
        invd[t] = 1.f / d;
    }
    __syncthreads();
    int d0 = t * 2;
    int g = d0 >> 4;
    float a0 = 0.f, a1 = 0.f;
    const float* ev = evalue + ((size_t)b*16384 + i*128) * 512 + d0;
    for (int j = 0; j < 128; ++j) {
        float aw = s[j][g];
        float2 e2 = *(const float2*)(ev + (size_t)j * 512);
        a0 += aw * e2.x; a1 += aw * e2.y;
    }
    float iv = invd[g];
    size_t o = (size_t)bi*512 + d0;
    v2[o]     = a0 * iv + vs[o];
    v2[o + 1] = a1 * iv + vs[o + 1];
}

// masked max-pool over i + cpool[b][n] = b_out[n] + sum_d pooled[d]*W_out[(512+d)*256+n]
__global__ void k_pool(const float* v2, const float* vmask, const float* W_out,
                       const float* b_out, float* cpool) {
    int b = blockIdx.x, t = threadIdx.x;
    __shared__ float pooled[512];
    for (int d = t; d < 512; d += 256) {
        float m = -1e30f;
        for (int i = 0; i < 128; ++i) {
            float val = v2[((size_t)(b*128 + i))*512 + d] - 1e9f * (1.f - vmask[b*128 + i]);
            m = fmaxf(m, val);
        }
        pooled[d] = m;
    }
    __syncthreads();
    float acc = b_out[t];
    for (int d = 0; d < 512; ++d) acc += pooled[d] * W_out[(512 + d)*256 + t];
    cpool[b*256 + t] = acc;
}

// v_out = silu(v2@W_out[0:512] + cpool[b]) ; 4 rows/block
__global__ void k_node_out(const float* v2, const float* W_out, const float* cpool,
                           float* out) {
    __shared__ float rv[4][512];
    int r0 = blockIdx.x * 4, t = threadIdx.x;
    for (int rr = 0; rr < 4; ++rr) {
        rv[rr][t]       = v2[(size_t)(r0+rr)*512 + t];
        rv[rr][t + 256] = v2[(size_t)(r0+rr)*512 + t + 256];
    }
    __syncthreads();
    int b = r0 >> 7;
    float acc[4];
    float cp = cpool[b*256 + t];
    for (int rr = 0; rr < 4; ++rr) acc[rr] = cp;
    for (int k = 0; k < 512; ++k) {
        float w = W_out[k*256 + t];
        #pragma unroll
        for (int rr = 0; rr < 4; ++rr) acc[rr] += rv[rr][k] * w;
    }
    for (int rr = 0; rr < 4; ++rr) out[(r0+rr)*256 + t] = siluf(acc[rr]);
}

extern "C" void kernel_launch(void* const* d_in, const int* in_sizes, int n_in,
                              void* d_out, int out_size, void* d_ws, size_t ws_size,
                              hipStream_t stream) {
    const float* v_f    = (const float*)d_in[0];
    const float* e_f    = (const float*)d_in[1];
    const float* p_pe   = (const float*)d_in[2];
    const float* t_pe   = (const float*)d_in[3];
    const float* emask  = (const float*)d_in[4];
    const float* vmask  = (const float*)d_in[5];
    const float* W_vpe  = (const float*)d_in[6];
    const float* b_vpe  = (const float*)d_in[7];
    const float* W_epe  = (const float*)d_in[8];
    const float* b_epe  = (const float*)d_in[9];
    const float* W_ev1  = (const float*)d_in[10];
    const float* b_ev1  = (const float*)d_in[11];
    const float* W_ev2  = (const float*)d_in[12];
    const float* b_ev2  = (const float*)d_in[13];
    const float* W_q    = (const float*)d_in[14];
    const float* b_q    = (const float*)d_in[15];
    const float* W_k    = (const float*)d_in[16];
    const float* b_k    = (const float*)d_in[17];
    const float* W_self = (const float*)d_in[18];
    const float* b_self = (const float*)d_in[19];
    const float* W_out  = (const float*)d_in[20];
    const float* b_out  = (const float*)d_in[21];

    float* out_v = (float*)d_out;                 // (4,128,256)
    float* out_e = (float*)d_out + 131072;        // (4,16384,512)

    char* w = (char*)d_ws;
    ushort_t* WT_epe = (ushort_t*)w; w += 512*512*2;
    ushort_t* WT_c   = (ushort_t*)w; w += 512*512*2;
    ushort_t* WT_ev2 = (ushort_t*)w; w += 512*512*2;
    float* c_v   = (float*)w; w += 4*256*4;
    float* c_e   = (float*)w; w += 4*512*4;
    float* v     = (float*)w; w += 512*256*4;
    float* qbuf  = (float*)w; w += 512*512*4;
    float* kbuf  = (float*)w; w += 512*512*4;
    float* vsbuf = (float*)w; w += 512*512*4;
    float* Pbuf  = (float*)w; w += 512*512*4;
    float* Qbuf  = (float*)w; w += 512*512*4;
    float* v2buf = (float*)w; w += 512*512*4;
    float* cpool = (float*)w; w += 4*256*4;
    ushort_t* e16 = (ushort_t*)w; w += (size_t)65536*512*2;
    ushort_t* h16 = (ushort_t*)w; w += (size_t)65536*512*2;

    k_prep<<<4, 512, 0, stream>>>(t_pe, W_vpe, b_vpe, W_epe, b_epe, c_v, c_e);
    k_transpose<<<dim3(512, 3), 256, 0, stream>>>(W_epe, W_ev1, W_ev2, WT_epe, WT_c, WT_ev2);
    k_node_v<<<128, 256, 0, stream>>>(v_f, p_pe, W_vpe, c_v, v);
    k_node_proj<<<dim3(128, 5), 256, 0, stream>>>(v, W_q, b_q, W_k, b_k, W_self, b_self,
                                                  W_ev1, b_ev1, qbuf, kbuf, vsbuf, Pbuf, Qbuf);
    k_gemm1<<<dim3(512, 4), 256, 0, stream>>>(e_f, WT_epe, c_e, e16);
    k_gemm_b<0><<<dim3(512, 4), 256, 0, stream>>>(e16, WT_c, Pbuf, Qbuf, h16, nullptr);
    k_gemm_b<1><<<dim3(512, 4), 256, 0, stream>>>(h16, WT_ev2, b_ev2, nullptr, nullptr, out_e);
    k_attn<<<512, 256, 0, stream>>>(qbuf, kbuf, emask, out_e, vsbuf, v2buf);
    k_pool<<<4, 256, 0, stream>>>(v2buf, vmask, W_out, b_out, cpool);
    k_node_out<<<128, 256, 0, stream>>>(v2buf, W_out, cpool, out_v);
}

// Round 2
// 671.345 us; speedup vs baseline: 1.0264x; 1.0264x over previous
//
#include <hip/hip_runtime.h>

typedef unsigned short ushort_t;
typedef __attribute__((ext_vector_type(8))) short bf16x8;
typedef __attribute__((ext_vector_type(4))) float f32x4;

__device__ __forceinline__ ushort_t f2bf(float f) {
    union { float f; unsigned u; } v; v.f = f;
    unsigned r = v.u + 0x7FFFu + ((v.u >> 16) & 1u);
    return (ushort_t)(r >> 16);
}
__device__ __forceinline__ float siluf(float x) { return x / (1.f + __expf(-x)); }
__device__ __forceinline__ float sigm(float x)  { return 1.f / (1.f + __expf(-x)); }

__device__ __forceinline__ void gl2lds16(const void* g, void* l) {
    __builtin_amdgcn_global_load_lds(
        (__attribute__((address_space(1))) void*)(const_cast<void*>(g)),
        (__attribute__((address_space(3))) void*)(l), 16, 0, 0);
}

// ---------------- tiny precompute kernels ----------------

__global__ void k_prep(const float* t_pe, const float* W_vpe, const float* b_vpe,
                       const float* W_epe, const float* b_epe,
                       float* c_v, float* c_e) {
    int b = blockIdx.x, t = threadIdx.x;  // 512 threads
    {
        float acc = b_epe[t];
        for (int u = 0; u < 100; ++u) acc += t_pe[b*100+u] * W_epe[(512+u)*512 + t];
        c_e[b*512 + t] = acc;
    }
    if (t < 256) {
        float acc = b_vpe[t];
        for (int u = 0; u < 100; ++u) acc += t_pe[b*100+u] * W_vpe[(456+u)*256 + t];
        c_v[b*256 + t] = acc;
    }
}

__global__ void k_transpose(const float* W_epe, const float* W_ev1, const float* W_ev2,
                            ushort_t* WT_epe, ushort_t* WT_c, ushort_t* WT_ev2) {
    int n = blockIdx.x;
    int mat = blockIdx.y;
    const float* src; ushort_t* dst;
    if (mat == 0)      { src = W_epe;            dst = WT_epe; }
    else if (mat == 1) { src = W_ev1 + 512*512;  dst = WT_c;   }
    else               { src = W_ev2;            dst = WT_ev2; }
    for (int k = threadIdx.x; k < 512; k += 256)
        dst[n*512 + k] = f2bf(src[k*512 + n]);
}

// e_f fp32 -> bf16, 8 elems/thread
__global__ __launch_bounds__(256) void k_cvt(const float* src, ushort_t* dst) {
    size_t id = (size_t)blockIdx.x * 256 + threadIdx.x;
    const float4* s = (const float4*)src + id * 2;
    float4 a = s[0], b = s[1];
    ushort4* d = (ushort4*)dst + id * 2;
    d[0] = make_ushort4(f2bf(a.x), f2bf(a.y), f2bf(a.z), f2bf(a.w));
    d[1] = make_ushort4(f2bf(b.x), f2bf(b.y), f2bf(b.z), f2bf(b.w));
}

__global__ void k_node_v(const float* v_f, const float* p_pe, const float* W_vpe,
                         const float* c_v, float* v) {
    __shared__ float rv[4][256];
    __shared__ float rp[4][200];
    int r0 = blockIdx.x * 4, t = threadIdx.x;
    for (int rr = 0; rr < 4; ++rr) {
        rv[rr][t] = v_f[(r0+rr)*256 + t];
        if (t < 200) rp[rr][t] = p_pe[(r0+rr)*200 + t];
    }
    __syncthreads();
    int b = r0 >> 7;
    float acc[4];
    float cv = c_v[b*256 + t];
    for (int rr = 0; rr < 4; ++rr) acc[rr] = cv;
    for (int k = 0; k < 256; ++k) {
        float w = W_vpe[k*256 + t];
        #pragma unroll
        for (int rr = 0; rr < 4; ++rr) acc[rr] += rv[rr][k] * w;
    }
    for (int k = 0; k < 200; ++k) {
        float w = W_vpe[(256+k)*256 + t];
        #pragma unroll
        for (int rr = 0; rr < 4; ++rr) acc[rr] += rp[rr][k] * w;
    }
    for (int rr = 0; rr < 4; ++rr) v[(r0+rr)*256 + t] = siluf(acc[rr]);
}

__global__ void k_node_proj(const float* v,
                            const float* W_q, const float* b_q,
                            const float* W_k, const float* b_k,
                            const float* W_self, const float* b_self,
                            const float* W_ev1, const float* b_ev1,
                            float* q, float* kk, float* vs, float* P, float* Q) {
    __shared__ float rv[4][256];
    int r0 = blockIdx.x * 4, which = blockIdx.y, t = threadIdx.x;
    for (int rr = 0; rr < 4; ++rr) rv[rr][t] = v[(r0+rr)*256 + t];
    __syncthreads();
    const float* W; const float* bias = nullptr; float* out; bool do_silu = false;
    if (which == 0)      { W = W_q;    bias = b_q;    out = q;  }
    else if (which == 1) { W = W_k;    bias = b_k;    out = kk; }
    else if (which == 2) { W = W_self; bias = b_self; out = vs; do_silu = true; }
    else if (which == 3) { W = W_ev1;  bias = b_ev1;  out = P;  }
    else                 { W = W_ev1 + 256*512;       out = Q;  }
    float acc[4][2] = {};
    for (int k = 0; k < 256; ++k) {
        float w0 = W[k*512 + t];
        float w1 = W[k*512 + t + 256];
        #pragma unroll
        for (int rr = 0; rr < 4; ++rr) {
            acc[rr][0] += rv[rr][k] * w0;
            acc[rr][1] += rv[rr][k] * w1;
        }
    }
    float bb0 = bias ? bias[t] : 0.f;
    float bb1 = bias ? bias[t + 256] : 0.f;
    for (int rr = 0; rr < 4; ++rr) {
        float x0 = acc[rr][0] + bb0;
        float x1 = acc[rr][1] + bb1;
        if (do_silu) { x0 = siluf(x0); x1 = siluf(x1); }
        out[(r0+rr)*512 + t]       = x0;
        out[(r0+rr)*512 + t + 256] = x1;
    }
}

// normalized attention weights: anorm[b,i,j,g] (4*128*128*32 fp32)
__global__ __launch_bounds__(256) void k_attw(const float* q, const float* kmat,
                                              const float* emask, float* anorm) {
    int bi = blockIdx.x; int b = bi >> 7, i = bi & 127;
    int t = threadIdx.x;
    __shared__ __align__(16) float qrow[512];
    __shared__ float s[128][33];
    __shared__ float invd[32];
    qrow[t]       = q[(size_t)bi*512 + t];
    qrow[t + 256] = q[(size_t)bi*512 + t + 256];
    __syncthreads();
    {
        int j = t >> 1, g0 = (t & 1) * 16;
        const float* kr = kmat + ((size_t)b*128 + j) * 512;
        float msk = emask[(size_t)b*16384 + i*128 + j];
        for (int gg = 0; gg < 16; ++gg) {
            int g = g0 + gg;
            const float4* k4 = (const float4*)(kr + g*16);
            const float4* q4 = (const float4*)(qrow + g*16);
            float acc = 0.f;
            #pragma unroll
            for (int c = 0; c < 4; ++c) {
                float4 kv = k4[c], qv = q4[c];
                acc += kv.x*qv.x + kv.y*qv.y + kv.z*qv.z + kv.w*qv.w;
            }
            s[j][g] = sigm(acc * 0.14433756729740645f) * msk;
        }
    }
    __syncthreads();
    if (t < 32) {
        float d = 1e-6f;
        for (int j = 0; j < 128; ++j) d += s[j][t];
        invd[t] = 1.f / d;
    }
    __syncthreads();
    float* dst = anorm + (size_t)bi * 4096;
    for (int idx = t; idx < 4096; idx += 256) {
        int j = idx >> 5, g = idx & 31;
        dst[idx] = s[j][g] * invd[g];
    }
}

// ---------------- unified MFMA GEMM (M=65536, K=512, N=512) ----------------
// 128x128 tile, 4 waves, mfma 16x16x32 bf16, BK=32, global_load_lds both ops.
// XCD swizzle: 4 n-tiles of an m-tile run consecutively on one XCD.
// MODE 0: epi silu(x + c_e[b][n]) -> bf16          (G1)
// MODE 1: epi silu(x + P[b,i] + Q[b,j]) -> bf16    (G2)
// MODE 2: epi x + b_ev2 -> fp32 out; fused weighted j-reduction -> v2 (G3+attn)
template <int MODE>
__global__ __launch_bounds__(256) void k_gemm(const ushort_t* A, const ushort_t* BT,
                                              const float* e0, const float* e1,
                                              const float* e2,
                                              ushort_t* out16, float* out32,
                                              float* v2out) {
    __shared__ __align__(16) ushort_t As[128*32];
    __shared__ __align__(16) ushort_t Bs[128*32];
    __shared__ float aw[(MODE == 2) ? 4096 : 4];
    __shared__ float red[(MODE == 2) ? 256 : 4];

    int lin = blockIdx.x;
    int xcd = lin & 7, idx = lin >> 3;
    int mt = xcd * 64 + (idx >> 2);
    int nt = idx & 3;
    int m0 = mt * 128, n0 = nt * 128;
    int t = threadIdx.x;
    int wv = t >> 6, lane = t & 63;
    int wm = (wv >> 1) * 64, wn = (wv & 1) * 64;
    int ml = lane & 15, quad = lane >> 4;
    f32x4 acc[4][4] = {};

    if (MODE == 2) {
        const float4* src = (const float4*)(e1 + (size_t)mt * 4096);
        float4* dst = (float4*)aw;
        for (int i = t; i < 1024; i += 256) dst[i] = src[i];
    }

    int srow = t >> 2, sseg = t & 3;
    const ushort_t* gA0 = A + (size_t)(m0 + srow) * 512 + sseg * 8;
    const ushort_t* gA1 = A + (size_t)(m0 + 64 + srow) * 512 + sseg * 8;
    const ushort_t* gB0 = BT + (size_t)(n0 + srow) * 512 + sseg * 8;
    const ushort_t* gB1 = BT + (size_t)(n0 + 64 + srow) * 512 + sseg * 8;
    ushort_t* lA0 = As + wv * 512;
    ushort_t* lA1 = As + 2048 + wv * 512;
    ushort_t* lB0 = Bs + wv * 512;
    ushort_t* lB1 = Bs + 2048 + wv * 512;

    for (int kk = 0; kk < 512; kk += 32) {
        gl2lds16(gA0 + kk, lA0);
        gl2lds16(gA1 + kk, lA1);
        gl2lds16(gB0 + kk, lB0);
        gl2lds16(gB1 + kk, lB1);
        __syncthreads();
        bf16x8 a[4], b[4];
        #pragma unroll
        for (int tm = 0; tm < 4; ++tm)
            a[tm] = *(const bf16x8*)(As + (wm + tm*16 + ml) * 32 + quad * 8);
        #pragma unroll
        for (int tn = 0; tn < 4; ++tn)
            b[tn] = *(const bf16x8*)(Bs + (wn + tn*16 + ml) * 32 + quad * 8);
        #pragma unroll
        for (int tm = 0; tm < 4; ++tm)
            #pragma unroll
            for (int tn = 0; tn < 4; ++tn)
                acc[tm][tn] = __builtin_amdgcn_mfma_f32_16x16x32_bf16(a[tm], b[tn], acc[tm][tn], 0, 0, 0);
        __syncthreads();
    }

    if (MODE == 2) {
        float partial[4] = {0.f, 0.f, 0.f, 0.f};
        #pragma unroll
        for (int tm = 0; tm < 4; ++tm)
            #pragma unroll
            for (int tn = 0; tn < 4; ++tn)
                #pragma unroll
                for (int r = 0; r < 4; ++r) {
                    int j  = wm + tm*16 + quad*4 + r;
                    int gn = n0 + wn + tn*16 + ml;
                    float x = acc[tm][tn][r] + e0[gn];
                    out32[((size_t)m0 + j) * 512 + gn] = x;
                    partial[tn] += aw[j * 32 + (gn >> 4)] * x;
                }
        #pragma unroll
        for (int tn = 0; tn < 4; ++tn) {
            float p = partial[tn];
            p += __shfl_down(p, 32);
            p += __shfl_down(p, 16);
            if (quad == 0 && lane < 16) red[wv * 64 + tn * 16 + ml] = p;
        }
        __syncthreads();
        if (t < 128) {
            int c = t, half = c >> 6, cl = c & 63;
            float tot = red[half * 64 + cl] + red[(half + 2) * 64 + cl];
            size_t o = (size_t)mt * 512 + n0 + c;
            v2out[o] = tot + e2[o];
        }
    } else {
        #pragma unroll
        for (int tm = 0; tm < 4; ++tm)
            #pragma unroll
            for (int tn = 0; tn < 4; ++tn)
                #pragma unroll
                for (int r = 0; r < 4; ++r) {
                    int gm = m0 + wm + tm*16 + quad*4 + r;
                    int gn = n0 + wn + tn*16 + ml;
                    float x = acc[tm][tn][r];
                    if (MODE == 0) {
                        x += e0[(gm >> 14) * 512 + gn];
                    } else {
                        int b_ = gm >> 14, ij = gm & 16383, i = ij >> 7, j = ij & 127;
                        x += e0[(size_t)((b_ << 7) + i) * 512 + gn]
                           + e1[(size_t)((b_ << 7) + j) * 512 + gn];
                    }
                    out16[(size_t)gm * 512 + gn] = f2bf(siluf(x));
                }
    }
}

// masked max-pool over i + cpool[b][n]
__global__ void k_pool(const float* v2, const float* vmask, const float* W_out,
                       const float* b_out, float* cpool) {
    int b = blockIdx.x, t = threadIdx.x;
    __shared__ float pooled[512];
    for (int d = t; d < 512; d += 256) {
        float m = -1e30f;
        for (int i = 0; i < 128; ++i) {
            float val = v2[((size_t)(b*128 + i))*512 + d] - 1e9f * (1.f - vmask[b*128 + i]);
            m = fmaxf(m, val);
        }
        pooled[d] = m;
    }
    __syncthreads();
    float acc = b_out[t];
    for (int d = 0; d < 512; ++d) acc += pooled[d] * W_out[(512 + d)*256 + t];
    cpool[b*256 + t] = acc;
}

__global__ void k_node_out(const float* v2, const float* W_out, const float* cpool,
                           float* out) {
    __shared__ float rv[4][512];
    int r0 = blockIdx.x * 4, t = threadIdx.x;
    for (int rr = 0; rr < 4; ++rr) {
        rv[rr][t]       = v2[(size_t)(r0+rr)*512 + t];
        rv[rr][t + 256] = v2[(size_t)(r0+rr)*512 + t + 256];
    }
    __syncthreads();
    int b = r0 >> 7;
    float acc[4];
    float cp = cpool[b*256 + t];
    for (int rr = 0; rr < 4; ++rr) acc[rr] = cp;
    for (int k = 0; k < 512; ++k) {
        float w = W_out[k*256 + t];
        #pragma unroll
        for (int rr = 0; rr < 4; ++rr) acc[rr] += rv[rr][k] * w;
    }
    for (int rr = 0; rr < 4; ++rr) out[(r0+rr)*256 + t] = siluf(acc[rr]);
}

extern "C" void kernel_launch(void* const* d_in, const int* in_sizes, int n_in,
                              void* d_out, int out_size, void* d_ws, size_t ws_size,
                              hipStream_t stream) {
    const float* v_f    = (const float*)d_in[0];
    const float* e_f    = (const float*)d_in[1];
    const float* p_pe   = (const float*)d_in[2];
    const float* t_pe   = (const float*)d_in[3];
    const float* emask  = (const float*)d_in[4];
    const float* vmask  = (const float*)d_in[5];
    const float* W_vpe  = (const float*)d_in[6];
    const float* b_vpe  = (const float*)d_in[7];
    const float* W_epe  = (const float*)d_in[8];
    const float* b_epe  = (const float*)d_in[9];
    const float* W_ev1  = (const float*)d_in[10];
    const float* b_ev1  = (const float*)d_in[11];
    const float* W_ev2  = (const float*)d_in[12];
    const float* b_ev2  = (const float*)d_in[13];
    const float* W_q    = (const float*)d_in[14];
    const float* b_q    = (const float*)d_in[15];
    const float* W_k    = (const float*)d_in[16];
    const float* b_k    = (const float*)d_in[17];
    const float* W_self = (const float*)d_in[18];
    const float* b_self = (const float*)d_in[19];
    const float* W_out  = (const float*)d_in[20];
    const float* b_out  = (const float*)d_in[21];

    float* out_v = (float*)d_out;                 // (4,128,256)
    float* out_e = (float*)d_out + 131072;        // (4,16384,512)

    char* w = (char*)d_ws;
    ushort_t* WT_epe = (ushort_t*)w; w += 512*512*2;
    ushort_t* WT_c   = (ushort_t*)w; w += 512*512*2;
    ushort_t* WT_ev2 = (ushort_t*)w; w += 512*512*2;
    float* c_v   = (float*)w; w += 4*256*4;
    float* c_e   = (float*)w; w += 4*512*4;
    float* v     = (float*)w; w += 512*256*4;
    float* qbuf  = (float*)w; w += 512*512*4;
    float* kbuf  = (float*)w; w += 512*512*4;
    float* vsbuf = (float*)w; w += 512*512*4;
    float* Pbuf  = (float*)w; w += 512*512*4;
    float* Qbuf  = (float*)w; w += 512*512*4;
    float* v2buf = (float*)w; w += 512*512*4;
    float* cpool = (float*)w; w += 4*256*4;
    float* anorm = (float*)w; w += (size_t)4*128*128*32*4;   // 8 MB
    ushort_t* e16  = (ushort_t*)w; w += (size_t)65536*512*2; // 67 MB
    ushort_t* ef16 = (ushort_t*)w; w += (size_t)65536*512*2; // 67 MB (aliased: h16)
    ushort_t* h16  = ef16;  // ef16 dead after G1 -> reuse for h16

    k_prep<<<4, 512, 0, stream>>>(t_pe, W_vpe, b_vpe, W_epe, b_epe, c_v, c_e);
    k_transpose<<<dim3(512, 3), 256, 0, stream>>>(W_epe, W_ev1, W_ev2, WT_epe, WT_c, WT_ev2);
    k_node_v<<<128, 256, 0, stream>>>(v_f, p_pe, W_vpe, c_v, v);
    k_node_proj<<<dim3(128, 5), 256, 0, stream>>>(v, W_q, b_q, W_k, b_k, W_self, b_self,
                                                  W_ev1, b_ev1, qbuf, kbuf, vsbuf, Pbuf, Qbuf);
    k_attw<<<512, 256, 0, stream>>>(qbuf, kbuf, emask, anorm);
    k_cvt<<<16384, 256, 0, stream>>>(e_f, ef16);
    k_gemm<0><<<2048, 256, 0, stream>>>(ef16, WT_epe, c_e, nullptr, nullptr, e16, nullptr, nullptr);
    k_gemm<1><<<2048, 256, 0, stream>>>(e16, WT_c, Pbuf, Qbuf, nullptr, h16, nullptr, nullptr);
    k_gemm<2><<<2048, 256, 0, stream>>>(h16, WT_ev2, b_ev2, anorm, vsbuf, nullptr, out_e, v2buf);
    k_pool<<<4, 256, 0, stream>>>(v2buf, vmask, W_out, b_out, cpool);
    k_node_out<<<128, 256, 0, stream>>>(v2buf, W_out, cpool, out_v);
}

// Round 3
// 648.292 us; speedup vs baseline: 1.0629x; 1.0356x over previous
//
#include <hip/hip_runtime.h>

typedef unsigned short ushort_t;
typedef __attribute__((ext_vector_type(8))) short bf16x8;
typedef __attribute__((ext_vector_type(4))) float f32x4;

__device__ __forceinline__ ushort_t f2bf(float f) {
    union { float f; unsigned u; } v; v.f = f;
    unsigned r = v.u + 0x7FFFu + ((v.u >> 16) & 1u);
    return (ushort_t)(r >> 16);
}
__device__ __forceinline__ float siluf(float x) { return x / (1.f + __expf(-x)); }
__device__ __forceinline__ float sigm(float x)  { return 1.f / (1.f + __expf(-x)); }

__device__ __forceinline__ void gl2lds16(const void* g, void* l) {
    __builtin_amdgcn_global_load_lds(
        (__attribute__((address_space(1))) void*)(const_cast<void*>(g)),
        (__attribute__((address_space(3))) void*)(l), 16, 0, 0);
}

// ---------------- fused weight transpose + PE-constant precompute ----------------
__global__ void k_pt(const float* W_epe, const float* W_ev1, const float* W_ev2,
                     const float* t_pe, const float* W_vpe, const float* b_vpe,
                     const float* b_epe,
                     ushort_t* WT_epe, ushort_t* WT_c, ushort_t* WT_ev2,
                     float* c_v, float* c_e) {
    int n = blockIdx.x, mat = blockIdx.y, t = threadIdx.x;
    if (mat == 3) {
        if (n < 4) {
            int b = n;
            for (int col = t; col < 512; col += 256) {
                float acc = b_epe[col];
                for (int u = 0; u < 100; ++u) acc += t_pe[b*100+u] * W_epe[(512+u)*512 + col];
                c_e[b*512 + col] = acc;
            }
            {
                float acc = b_vpe[t];
                for (int u = 0; u < 100; ++u) acc += t_pe[b*100+u] * W_vpe[(456+u)*256 + t];
                c_v[b*256 + t] = acc;
            }
        }
        return;
    }
    const float* src; ushort_t* dst;
    if (mat == 0)      { src = W_epe;            dst = WT_epe; }
    else if (mat == 1) { src = W_ev1 + 512*512;  dst = WT_c;   }
    else               { src = W_ev2;            dst = WT_ev2; }
    for (int k = t; k < 512; k += 256)
        dst[n*512 + k] = f2bf(src[k*512 + n]);
}

// ---------------- node feature kernels ----------------
__global__ void k_node_v(const float* v_f, const float* p_pe, const float* W_vpe,
                         const float* c_v, float* v) {
    __shared__ float rv[4][256];
    __shared__ float rp[4][200];
    int r0 = blockIdx.x * 4, t = threadIdx.x;
    for (int rr = 0; rr < 4; ++rr) {
        rv[rr][t] = v_f[(r0+rr)*256 + t];
        if (t < 200) rp[rr][t] = p_pe[(r0+rr)*200 + t];
    }
    __syncthreads();
    int b = r0 >> 7;
    float acc[4];
    float cv = c_v[b*256 + t];
    for (int rr = 0; rr < 4; ++rr) acc[rr] = cv;
    for (int k = 0; k < 256; ++k) {
        float w = W_vpe[k*256 + t];
        #pragma unroll
        for (int rr = 0; rr < 4; ++rr) acc[rr] += rv[rr][k] * w;
    }
    for (int k = 0; k < 200; ++k) {
        float w = W_vpe[(256+k)*256 + t];
        #pragma unroll
        for (int rr = 0; rr < 4; ++rr) acc[rr] += rp[rr][k] * w;
    }
    for (int rr = 0; rr < 4; ++rr) v[(r0+rr)*256 + t] = siluf(acc[rr]);
}

__global__ void k_node_proj(const float* v,
                            const float* W_q, const float* b_q,
                            const float* W_k, const float* b_k,
                            const float* W_self, const float* b_self,
                            const float* W_ev1, const float* b_ev1,
                            float* q, float* kk, float* vs, float* P, float* Q) {
    __shared__ float rv[4][256];
    int r0 = blockIdx.x * 4, which = blockIdx.y, t = threadIdx.x;
    for (int rr = 0; rr < 4; ++rr) rv[rr][t] = v[(r0+rr)*256 + t];
    __syncthreads();
    const float* W; const float* bias = nullptr; float* out; bool do_silu = false;
    if (which == 0)      { W = W_q;    bias = b_q;    out = q;  }
    else if (which == 1) { W = W_k;    bias = b_k;    out = kk; }
    else if (which == 2) { W = W_self; bias = b_self; out = vs; do_silu = true; }
    else if (which == 3) { W = W_ev1;  bias = b_ev1;  out = P;  }
    else                 { W = W_ev1 + 256*512;       out = Q;  }
    float acc[4][2] = {};
    for (int k = 0; k < 256; ++k) {
        float w0 = W[k*512 + t];
        float w1 = W[k*512 + t + 256];
        #pragma unroll
        for (int rr = 0; rr < 4; ++rr) {
            acc[rr][0] += rv[rr][k] * w0;
            acc[rr][1] += rv[rr][k] * w1;
        }
    }
    float bb0 = bias ? bias[t] : 0.f;
    float bb1 = bias ? bias[t + 256] : 0.f;
    for (int rr = 0; rr < 4; ++rr) {
        float x0 = acc[rr][0] + bb0;
        float x1 = acc[rr][1] + bb1;
        if (do_silu) { x0 = siluf(x0); x1 = siluf(x1); }
        out[(r0+rr)*512 + t]       = x0;
        out[(r0+rr)*512 + t + 256] = x1;
    }
}

// normalized attention weights: anorm[b,i,j,g] (4*128*128*32 fp32)
__global__ __launch_bounds__(256) void k_attw(const float* q, const float* kmat,
                                              const float* emask, float* anorm) {
    int bi = blockIdx.x; int b = bi >> 7, i = bi & 127;
    int t = threadIdx.x;
    __shared__ __align__(16) float qrow[512];
    __shared__ float s[128][33];
    __shared__ float invd[32];
    qrow[t]       = q[(size_t)bi*512 + t];
    qrow[t + 256] = q[(size_t)bi*512 + t + 256];
    __syncthreads();
    {
        int j = t >> 1, g0 = (t & 1) * 16;
        const float* kr = kmat + ((size_t)b*128 + j) * 512;
        float msk = emask[(size_t)b*16384 + i*128 + j];
        for (int gg = 0; gg < 16; ++gg) {
            int g = g0 + gg;
            const float4* k4 = (const float4*)(kr + g*16);
            const float4* q4 = (const float4*)(qrow + g*16);
            float acc = 0.f;
            #pragma unroll
            for (int c = 0; c < 4; ++c) {
                float4 kv = k4[c], qv = q4[c];
                acc += kv.x*qv.x + kv.y*qv.y + kv.z*qv.z + kv.w*qv.w;
            }
            s[j][g] = sigm(acc * 0.14433756729740645f) * msk;
        }
    }
    __syncthreads();
    if (t < 32) {
        float d = 1e-6f;
        for (int j = 0; j < 128; ++j) d += s[j][t];
        invd[t] = 1.f / d;
    }
    __syncthreads();
    float* dst = anorm + (size_t)bi * 4096;
    for (int idx = t; idx < 4096; idx += 256) {
        int j = idx >> 5, g = idx & 31;
        dst[idx] = s[j][g] * invd[g];
    }
}

// ---------------- unified MFMA GEMM (M=65536, K=512, N=512) ----------------
// 128x128 tile, 4 waves, 16x16x32 bf16 MFMA, BK=64 (two 32-k half-slabs),
// double-buffered LDS (one barrier per iter), XCD-swizzled grid.
// MODE 0: A = e_f fp32 (inline cvt via VGPR, pipelined); epi silu(x+c_e) -> bf16
// MODE 1: A = bf16; epi silu(x + P[b,i] + Q[b,j]) -> bf16
// MODE 2: A = bf16; epi x + b_ev2 -> fp32; fused weighted j-reduction -> v2
// LDS: A halves [0,16K) ushorts, B halves [16K,32K) = exactly 64 KB.
template <int MODE>
__global__ __launch_bounds__(256) void k_gemm(const void* Aptr, const ushort_t* BT,
                                              const float* e0, const float* e1,
                                              const float* e2,
                                              ushort_t* out16, float* out32,
                                              float* v2out) {
    __shared__ __align__(16) ushort_t smem[32768];
    int lin = blockIdx.x;
    int xcd = lin & 7, idx = lin >> 3;
    int mt = xcd * 64 + (idx >> 2);
    int nt = idx & 3;
    int m0 = mt * 128, n0 = nt * 128;
    int t = threadIdx.x;
    int wv = t >> 6, lane = t & 63;
    int wm = (wv >> 1) * 64, wn = (wv & 1) * 64;
    int ml = lane & 15, quad = lane >> 4;
    f32x4 acc[4][4] = {};

    int brow = t >> 2, bseg = t & 3;
    const ushort_t* gB = BT + (size_t)(n0 + brow) * 512 + bseg * 8;
    const ushort_t* gA16 = (const ushort_t*)Aptr + (size_t)(m0 + brow) * 512 + bseg * 8;
    const float*    gA32 = (const float*)Aptr + (size_t)(m0 + (t >> 4)) * 512 + (t & 15) * 4;

    float4 f[8];
    int ahalf = (t >> 3) & 1;            // (t&15)>=8 -> k-half 1
    int acol  = (t & 7) * 4;             // local k (ushorts) within half

    auto issueB = [&](int it, int d) {
        int kk = it * 64;
        #pragma unroll
        for (int s = 0; s < 2; ++s)
            #pragma unroll
            for (int g = 0; g < 2; ++g)
                gl2lds16(gB + (size_t)g * 64 * 512 + kk + s * 32,
                         smem + 16384 + d * 8192 + s * 4096 + g * 2048 + wv * 512);
    };
    auto issueA16 = [&](int it, int d) {
        int kk = it * 64;
        #pragma unroll
        for (int s = 0; s < 2; ++s)
            #pragma unroll
            for (int g = 0; g < 2; ++g)
                gl2lds16(gA16 + (size_t)g * 64 * 512 + kk + s * 32,
                         smem + d * 8192 + s * 4096 + g * 2048 + wv * 512);
    };
    auto loadA32 = [&](int it) {
        int kk = it * 64;
        #pragma unroll
        for (int j = 0; j < 8; ++j)
            f[j] = *(const float4*)(gA32 + (size_t)(j * 16) * 512 + kk);
    };
    auto writeA32 = [&](int d) {
        #pragma unroll
        for (int j = 0; j < 8; ++j) {
            int row = (t >> 4) + j * 16;
            ushort_t* dst = smem + d * 8192 + ahalf * 4096 + row * 32 + acol;
            float4 v4 = f[j];
            *(ushort4*)dst = make_ushort4(f2bf(v4.x), f2bf(v4.y), f2bf(v4.z), f2bf(v4.w));
        }
    };
    auto compute = [&](int d) {
        #pragma unroll
        for (int s = 0; s < 2; ++s) {
            bf16x8 a[4], b[4];
            #pragma unroll
            for (int tm = 0; tm < 4; ++tm)
                a[tm] = *(const bf16x8*)(smem + d * 8192 + s * 4096 + (wm + tm*16 + ml) * 32 + quad * 8);
            #pragma unroll
            for (int tn = 0; tn < 4; ++tn)
                b[tn] = *(const bf16x8*)(smem + 16384 + d * 8192 + s * 4096 + (wn + tn*16 + ml) * 32 + quad * 8);
            #pragma unroll
            for (int tm = 0; tm < 4; ++tm)
                #pragma unroll
                for (int tn = 0; tn < 4; ++tn)
                    acc[tm][tn] = __builtin_amdgcn_mfma_f32_16x16x32_bf16(a[tm], b[tn], acc[tm][tn], 0, 0, 0);
        }
    };

    // prologue: fill buffer 0
    if (MODE == 0) { issueB(0, 0); loadA32(0); writeA32(0); }
    else           { issueB(0, 0); issueA16(0, 0); }

    for (int it = 0; it < 8; ++it) {
        __syncthreads();                     // drains vmcnt+lgkm: buf[it&1] ready, other buf free
        int nd = (it + 1) & 1;
        if (MODE == 0) {
            if (it < 7) { issueB(it + 1, nd); loadA32(it + 1); }
            compute(it & 1);
            if (it < 7) writeA32(nd);
        } else {
            if (it < 7) { issueB(it + 1, nd); issueA16(it + 1, nd); }
            compute(it & 1);
        }
    }

    int gn0 = n0 + wn + ml;
    if (MODE == 2) {
        __syncthreads();
        float* aw  = (float*)smem;           // 4096 floats (epilogue overlay)
        float* red = aw + 4096;              // 256 floats
        {
            const float4* src = (const float4*)(e1 + (size_t)mt * 4096);
            float4* dw = (float4*)aw;
            for (int i2 = t; i2 < 1024; i2 += 256) dw[i2] = src[i2];
        }
        __syncthreads();
        float bv[4];
        #pragma unroll
        for (int tn = 0; tn < 4; ++tn) bv[tn] = e0[gn0 + tn*16];
        float partial[4] = {0.f, 0.f, 0.f, 0.f};
        #pragma unroll
        for (int tm = 0; tm < 4; ++tm)
            #pragma unroll
            for (int tn = 0; tn < 4; ++tn)
                #pragma unroll
                for (int r = 0; r < 4; ++r) {
                    int j  = wm + tm*16 + quad*4 + r;
                    int gn = gn0 + tn*16;
                    float x = acc[tm][tn][r] + bv[tn];
                    out32[((size_t)m0 + j) * 512 + gn] = x;
                    partial[tn] += aw[j * 32 + (gn >> 4)] * x;
                }
        #pragma unroll
        for (int tn = 0; tn < 4; ++tn) {
            float p = partial[tn];
            p += __shfl_down(p, 32);
            p += __shfl_down(p, 16);
            if (quad == 0 && lane < 16) red[wv * 64 + tn * 16 + ml] = p;
        }
        __syncthreads();
        if (t < 128) {
            int c = t, half = c >> 6, cl = c & 63;
            float tot = red[half * 64 + cl] + red[(half + 2) * 64 + cl];
            size_t o = (size_t)mt * 512 + n0 + c;
            v2out[o] = tot + e2[o];
        }
    } else if (MODE == 1) {
        int bi = mt;
        int brow0 = (bi >> 7) << 7;          // b*128
        float Pv[4];
        #pragma unroll
        for (int tn = 0; tn < 4; ++tn) Pv[tn] = e0[(size_t)bi * 512 + gn0 + tn*16];
        #pragma unroll
        for (int tm = 0; tm < 4; ++tm)
            #pragma unroll
            for (int tn = 0; tn < 4; ++tn)
                #pragma unroll
                for (int r = 0; r < 4; ++r) {
                    int j  = wm + tm*16 + quad*4 + r;
                    int gn = gn0 + tn*16;
                    float x = acc[tm][tn][r] + Pv[tn]
                            + e1[(size_t)(brow0 + j) * 512 + gn];
                    out16[((size_t)m0 + j) * 512 + gn] = f2bf(siluf(x));
                }
    } else {
        int b_ = mt >> 7;
        float cv[4];
        #pragma unroll
        for (int tn = 0; tn < 4; ++tn) cv[tn] = e0[b_ * 512 + gn0 + tn*16];
        #pragma unroll
        for (int tm = 0; tm < 4; ++tm)
            #pragma unroll
            for (int tn = 0; tn < 4; ++tn)
                #pragma unroll
                for (int r = 0; r < 4; ++r) {
                    int j  = wm + tm*16 + quad*4 + r;
                    int gn = gn0 + tn*16;
                    float x = acc[tm][tn][r] + cv[tn];
                    out16[((size_t)m0 + j) * 512 + gn] = f2bf(siluf(x));
                }
    }
}

// ---------------- fused masked max-pool + output projection ----------------
__global__ __launch_bounds__(256) void k_out(const float* v2, const float* vmask,
                                             const float* W_out, const float* b_out,
                                             float* out) {
    __shared__ float pooled[512];
    __shared__ float rv[4][512];
    __shared__ float vm[128];
    int r0 = blockIdx.x * 4, t = threadIdx.x, b = r0 >> 7;
    if (t < 128) vm[t] = -1e9f * (1.f - vmask[b*128 + t]);
    for (int rr = 0; rr < 4; ++rr) {
        rv[rr][t]       = v2[(size_t)(r0+rr)*512 + t];
        rv[rr][t + 256] = v2[(size_t)(r0+rr)*512 + t + 256];
    }
    __syncthreads();
    for (int d = t; d < 512; d += 256) {
        float m = -1e30f;
        for (int i = 0; i < 128; ++i)
            m = fmaxf(m, v2[((size_t)(b*128 + i))*512 + d] + vm[i]);
        pooled[d] = m;
    }
    __syncthreads();
    float cp = b_out[t];
    for (int d = 0; d < 512; ++d) cp += pooled[d] * W_out[(512 + d)*256 + t];
    float acc[4];
    for (int rr = 0; rr < 4; ++rr) acc[rr] = cp;
    for (int k = 0; k < 512; ++k) {
        float w = W_out[k*256 + t];
        #pragma unroll
        for (int rr = 0; rr < 4; ++rr) acc[rr] += rv[rr][k] * w;
    }
    for (int rr = 0; rr < 4; ++rr) out[(r0+rr)*256 + t] = siluf(acc[rr]);
}

extern "C" void kernel_launch(void* const* d_in, const int* in_sizes, int n_in,
                              void* d_out, int out_size, void* d_ws, size_t ws_size,
                              hipStream_t stream) {
    const float* v_f    = (const float*)d_in[0];
    const float* e_f    = (const float*)d_in[1];
    const float* p_pe   = (const float*)d_in[2];
    const float* t_pe   = (const float*)d_in[3];
    const float* emask  = (const float*)d_in[4];
    const float* vmask  = (const float*)d_in[5];
    const float* W_vpe  = (const float*)d_in[6];
    const float* b_vpe  = (const float*)d_in[7];
    const float* W_epe  = (const float*)d_in[8];
    const float* b_epe  = (const float*)d_in[9];
    const float* W_ev1  = (const float*)d_in[10];
    const float* b_ev1  = (const float*)d_in[11];
    const float* W_ev2  = (const float*)d_in[12];
    const float* b_ev2  = (const float*)d_in[13];
    const float* W_q    = (const float*)d_in[14];
    const float* b_q    = (const float*)d_in[15];
    const float* W_k    = (const float*)d_in[16];
    const float* b_k    = (const float*)d_in[17];
    const float* W_self = (const float*)d_in[18];
    const float* b_self = (const float*)d_in[19];
    const float* W_out  = (const float*)d_in[20];
    const float* b_out  = (const float*)d_in[21];

    float* out_v = (float*)d_out;                 // (4,128,256)
    float* out_e = (float*)d_out + 131072;        // (4,16384,512)

    char* w = (char*)d_ws;
    ushort_t* WT_epe = (ushort_t*)w; w += 512*512*2;
    ushort_t* WT_c   = (ushort_t*)w; w += 512*512*2;
    ushort_t* WT_ev2 = (ushort_t*)w; w += 512*512*2;
    float* c_v   = (float*)w; w += 4*256*4;
    float* c_e   = (float*)w; w += 4*512*4;
    float* v     = (float*)w; w += 512*256*4;
    float* qbuf  = (float*)w; w += 512*512*4;
    float* kbuf  = (float*)w; w += 512*512*4;
    float* vsbuf = (float*)w; w += 512*512*4;
    float* Pbuf  = (float*)w; w += 512*512*4;
    float* Qbuf  = (float*)w; w += 512*512*4;
    float* v2buf = (float*)w; w += 512*512*4;
    float* anorm = (float*)w; w += (size_t)4*128*128*32*4;   // 8 MB
    ushort_t* e16 = (ushort_t*)w; w += (size_t)65536*512*2;  // 67 MB
    ushort_t* h16 = (ushort_t*)w; w += (size_t)65536*512*2;  // 67 MB

    k_pt<<<dim3(512, 4), 256, 0, stream>>>(W_epe, W_ev1, W_ev2, t_pe, W_vpe, b_vpe, b_epe,
                                           WT_epe, WT_c, WT_ev2, c_v, c_e);
    k_node_v<<<128, 256, 0, stream>>>(v_f, p_pe, W_vpe, c_v, v);
    k_node_proj<<<dim3(128, 5), 256, 0, stream>>>(v, W_q, b_q, W_k, b_k, W_self, b_self,
                                                  W_ev1, b_ev1, qbuf, kbuf, vsbuf, Pbuf, Qbuf);
    k_attw<<<512, 256, 0, stream>>>(qbuf, kbuf, emask, anorm);
    k_gemm<0><<<2048, 256, 0, stream>>>(e_f, WT_epe, c_e, nullptr, nullptr, e16, nullptr, nullptr);
    k_gemm<1><<<2048, 256, 0, stream>>>(e16, WT_c, Pbuf, Qbuf, nullptr, h16, nullptr, nullptr);
    k_gemm<2><<<2048, 256, 0, stream>>>(h16, WT_ev2, b_ev2, anorm, vsbuf, nullptr, out_e, v2buf);
    k_out<<<128, 256, 0, stream>>>(v2buf, vmask, W_out, b_out, out_v);
}